// Round 2
// baseline (645.366 us; speedup 1.0000x reference)
//
#include <hip/hip_runtime.h>
#include <cstdint>

typedef __bf16 bf16x8 __attribute__((ext_vector_type(8)));
typedef float f32x4 __attribute__((ext_vector_type(4)));

__device__ __forceinline__ float b2f(unsigned short u) {
  union { uint32_t i; float f; } v; v.i = ((uint32_t)u) << 16; return v.f;
}
__device__ __forceinline__ unsigned short f2b(float f) {
  union { float f; uint32_t i; } v; v.f = f;
  uint32_t u = v.i;
  u += 0x7fffu + ((u >> 16) & 1u);   // round-to-nearest-even
  return (unsigned short)(u >> 16);
}

// async global->LDS, 16B per lane. LDS dest must be wave-uniform base + lane*16
// (our layouts are exactly lane-contiguous).
__device__ __forceinline__ void gload_lds16(const void* g, void* l) {
  __builtin_amdgcn_global_load_lds(
      (const __attribute__((address_space(1))) uint32_t*)(uintptr_t)g,
      (__attribute__((address_space(3))) uint32_t*)(uint32_t)(uintptr_t)l, 16, 0, 0);
}

// ---------------------------------------------------------------------------
// K0: W (fp32 1024x1024) -> Wb (bf16)
// ---------------------------------------------------------------------------
__global__ __launch_bounds__(256) void k_wconv(const float* __restrict__ W,
                                               unsigned short* __restrict__ Wb) {
  const size_t idx = ((size_t)blockIdx.x * 256 + threadIdx.x) * 4;
  float4 d = *(const float4*)(W + idx);
  ushort4 o;
  o.x = f2b(d.x); o.y = f2b(d.y); o.z = f2b(d.z); o.w = f2b(d.w);
  *(ushort4*)(Wb + idx) = o;
}

// ---------------------------------------------------------------------------
// K1: Haar analysis (row 0 of A) fused with transpose:
//   xs[p][b][c][8192] (fp32) -> sc_t[b][ls][j=p*128+c] (bf16), ls in [0,4096)
// tile: 64 j x 64 ls per block, LDS transpose (row stride 72 keeps 16B align)
// ---------------------------------------------------------------------------
__global__ __launch_bounds__(256) void k_analysis(const float* __restrict__ xs,
                                                  const float* __restrict__ A,
                                                  unsigned short* __restrict__ sct) {
  __shared__ __align__(16) unsigned short lt[64 * 72];
  const int t = threadIdx.x;
  const int bx = blockIdx.x;   // ls-tile 0..63
  const int by = blockIdx.y;   // j-tile 0..15
  const int bz = blockIdx.z;   // b
  const float a00 = A[0], a01 = A[1];
  const int r = t >> 2, s = t & 3;
  const int j = by * 64 + r;
  const int p = j >> 7, c = j & 127;
  const float* xr = xs + ((size_t)(p * 8 + bz) * 128 + c) * 8192 + bx * 128;
#pragma unroll
  for (int a = 0; a < 8; ++a) {
    float4 d = *(const float4*)(xr + (s + 4 * a) * 4);
    int lsl = (s + 4 * a) * 2;
    lt[lsl * 72 + r]       = f2b(a00 * d.x + a01 * d.y);
    lt[(lsl + 1) * 72 + r] = f2b(a00 * d.z + a01 * d.w);
  }
  __syncthreads();
  const int lsr = t >> 2, ss = t & 3;
  uint4 o0 = *(const uint4*)&lt[lsr * 72 + ss * 16];
  uint4 o1 = *(const uint4*)&lt[lsr * 72 + ss * 16 + 8];
  size_t oidx = ((size_t)bz * 4096 + bx * 64 + lsr) * 1024 + by * 64 + ss * 16;
  *(uint4*)(sct + oidx) = o0;
  *(uint4*)(sct + oidx + 8) = o1;
}

// ---------------------------------------------------------------------------
// K2: smix[b][i][l] = sum_j Wb[i][j] * sc_t[b][l][j]   (bf16 MFMA, fp32 acc)
// m97 structure: BM=BN=128, BK=64, 256 thr (4 waves, 2x2), 16x16x32 bf16 MFMA,
// global_load_lds width 16, both operands k-contiguous in LDS.
// ---------------------------------------------------------------------------
__global__ __launch_bounds__(256) void k_gemm(const unsigned short* __restrict__ Wb,
                                              const unsigned short* __restrict__ sct,
                                              unsigned short* __restrict__ smix) {
  __shared__ __align__(16) unsigned short lA[128 * 64];  // [i_loc][k_loc]
  __shared__ __align__(16) unsigned short lB[128 * 64];  // [l_loc][k_loc]
  const int t = threadIdx.x;
  const int i0 = blockIdx.x * 128;   // i-block fastest -> per-XCD W-slice locality
  const int l0 = blockIdx.y * 128;
  const int bz = blockIdx.z;
  const int lane = t & 63, wv = t >> 6;
  const int wm = wv & 1, wn = wv >> 1;
  const int lm = lane & 15, q = lane >> 4;
  const int srow = t >> 3;           // 0..31
  const int scol = (t & 7) * 8;      // element col (16B)
  f32x4 acc[4][4] = {};
  for (int kt = 0; kt < 16; ++kt) {
    __syncthreads();
    const int k0 = kt * 64;
#pragma unroll
    for (int a = 0; a < 4; ++a) {
      int rowa = a * 32 + srow;
      gload_lds16(Wb + ((size_t)(i0 + rowa) * 1024 + k0 + scol),
                  (char*)lA + a * 4096 + t * 16);
      gload_lds16(sct + (((size_t)bz * 4096 + l0 + rowa) * 1024 + k0 + scol),
                  (char*)lB + a * 4096 + t * 16);
    }
    __syncthreads();
#pragma unroll
    for (int kk = 0; kk < 2; ++kk) {
      bf16x8 aF[4], bF[4];
#pragma unroll
      for (int mi = 0; mi < 4; ++mi)
        aF[mi] = *(const bf16x8*)&lA[(wm * 64 + mi * 16 + lm) * 64 + kk * 32 + q * 8];
#pragma unroll
      for (int ni = 0; ni < 4; ++ni)
        bF[ni] = *(const bf16x8*)&lB[(wn * 64 + ni * 16 + lm) * 64 + kk * 32 + q * 8];
#pragma unroll
      for (int mi = 0; mi < 4; ++mi)
#pragma unroll
        for (int ni = 0; ni < 4; ++ni)
          acc[mi][ni] = __builtin_amdgcn_mfma_f32_16x16x32_bf16(aF[mi], bF[ni], acc[mi][ni], 0, 0, 0);
    }
  }
  // C/D layout (m89-verified): col = lane&15, row = (lane>>4)*4 + reg
  const size_t base = ((size_t)bz * 1024 + i0 + wm * 64) * 4096 + (size_t)(l0 + wn * 64);
#pragma unroll
  for (int mi = 0; mi < 4; ++mi)
#pragma unroll
    for (int ni = 0; ni < 4; ++ni)
#pragma unroll
      for (int rr = 0; rr < 4; ++rr)
        smix[base + (size_t)(mi * 16 + q * 4 + rr) * 4096 + ni * 16 + lm] = f2b(acc[mi][ni][rr]);
}

// ---------------------------------------------------------------------------
// K3: per-channel BN stats over (B, Ls)=32768 samples + fold gamma/beta:
//   scale[i] = gamma*rstd, shift[i] = beta - mean*gamma*rstd
// one block per channel -> no atomics, no ws zero-init needed.
// ---------------------------------------------------------------------------
__global__ __launch_bounds__(256) void k_stats(const unsigned short* __restrict__ smix,
                                               const float* __restrict__ gamma,
                                               const float* __restrict__ beta,
                                               float* __restrict__ scale,
                                               float* __restrict__ shift) {
  const int i = blockIdx.x;
  const int t = threadIdx.x;
  float s = 0.f, s2 = 0.f;
  for (int b = 0; b < 8; ++b) {
    const unsigned short* pr = smix + ((size_t)b * 1024 + i) * 4096 + t * 16;
    union { uint4 v; unsigned short u[8]; } d0, d1;
    d0.v = *(const uint4*)pr;
    d1.v = *(const uint4*)(pr + 8);
#pragma unroll
    for (int e = 0; e < 8; ++e) {
      float v0 = b2f(d0.u[e]), v1 = b2f(d1.u[e]);
      s += v0 + v1;
      s2 += v0 * v0 + v1 * v1;
    }
  }
#pragma unroll
  for (int o = 32; o > 0; o >>= 1) {
    s += __shfl_down(s, o, 64);
    s2 += __shfl_down(s2, o, 64);
  }
  __shared__ float ps[4], ps2[4];
  const int lane = t & 63, wv = t >> 6;
  if (lane == 0) { ps[wv] = s; ps2[wv] = s2; }
  __syncthreads();
  if (t == 0) {
    float S = ps[0] + ps[1] + ps[2] + ps[3];
    float S2 = ps2[0] + ps2[1] + ps2[2] + ps2[3];
    const float inv = 1.0f / 32768.0f;
    float mean = S * inv;
    float var = S2 * inv - mean * mean;   // biased, matches jnp .var
    float rstd = rsqrtf(var + 1e-5f);
    float g = gamma[i] * rstd;
    scale[i] = g;
    shift[i] = beta[i] - mean * g;
  }
}

// ---------------------------------------------------------------------------
// K4: first output half (l in [0,4096)): BN+GELU(exact erf) on smix pairs,
// then synthesis butterfly with S. Fully coalesced both sides. fp32 out.
// ---------------------------------------------------------------------------
__global__ __launch_bounds__(256) void k_synth_sc(const unsigned short* __restrict__ smix,
                                                  const float* __restrict__ S,
                                                  const float* __restrict__ scale,
                                                  const float* __restrict__ shift,
                                                  float* __restrict__ out) {
  const float s00 = S[0], s01 = S[1], s10 = S[2], s11 = S[3];
  const size_t tid = (size_t)blockIdx.x * 256 + threadIdx.x;
  const size_t f = tid * 16;                 // flat index into smix [b][i][l]
  const int b = (int)(f >> 22);
  const int i = (int)((f >> 12) & 1023);
  const int l0 = (int)(f & 4095);
  const float sc_i = scale[i], sh_i = shift[i];
  union { uint4 v; unsigned short u[8]; } d0, d1;
  d0.v = *(const uint4*)(smix + f);
  d1.v = *(const uint4*)(smix + f + 8);
  float cv[16];
#pragma unroll
  for (int e = 0; e < 8; ++e) {
    float z0 = b2f(d0.u[e]) * sc_i + sh_i;
    cv[e] = 0.5f * z0 * (1.0f + erff(z0 * 0.7071067811865475f));
    float z1 = b2f(d1.u[e]) * sc_i + sh_i;
    cv[8 + e] = 0.5f * z1 * (1.0f + erff(z1 * 0.7071067811865475f));
  }
  float ov[16];
#pragma unroll
  for (int m = 0; m < 8; ++m) {
    float c0 = cv[2 * m], c1 = cv[2 * m + 1];
    ov[2 * m] = s00 * c0 + s01 * c1;
    ov[2 * m + 1] = s10 * c0 + s11 * c1;
  }
  const int p = i >> 7, cc = i & 127;
  size_t ob = ((size_t)(p * 8 + b) * 128 + cc) * 8192 + l0;
#pragma unroll
  for (int v = 0; v < 4; ++v)
    *(float4*)(out + ob + v * 4) = *(float4*)&ov[v * 4];
}

// ---------------------------------------------------------------------------
// K5: second output half (l in [4096,8192)): recompute det from xs (row 1 of
// A), synthesis butterfly with S. fp32 in/out.
// ---------------------------------------------------------------------------
__global__ __launch_bounds__(256) void k_synth_det(const float* __restrict__ xs,
                                                   const float* __restrict__ A,
                                                   const float* __restrict__ S,
                                                   float* __restrict__ out) {
  const float a10 = A[2], a11 = A[3];
  const float s00 = S[0], s01 = S[1], s10 = S[2], s11 = S[3];
  const size_t tid = (size_t)blockIdx.x * 256 + threadIdx.x;
  const size_t f = tid * 16;            // flat index over [8192 rows][4096]
  const size_t r = f >> 12;             // row = (p*8+b)*128+c
  const int off = (int)(f & 4095);
  const float* xr = xs + r * 8192 + 2 * (size_t)off;
  float xv[32];
#pragma unroll
  for (int a = 0; a < 8; ++a) {
    float4 d = *(const float4*)(xr + a * 4);
    xv[a * 4 + 0] = d.x; xv[a * 4 + 1] = d.y; xv[a * 4 + 2] = d.z; xv[a * 4 + 3] = d.w;
  }
  float ov[16];
#pragma unroll
  for (int m = 0; m < 8; ++m) {
    float c0 = a10 * xv[4 * m] + a11 * xv[4 * m + 1];
    float c1 = a10 * xv[4 * m + 2] + a11 * xv[4 * m + 3];
    ov[2 * m] = s00 * c0 + s01 * c1;
    ov[2 * m + 1] = s10 * c0 + s11 * c1;
  }
  size_t ob = r * 8192 + 4096 + off;
#pragma unroll
  for (int v = 0; v < 4; ++v)
    *(float4*)(out + ob + v * 4) = *(float4*)&ov[v * 4];
}

extern "C" void kernel_launch(void* const* d_in, const int* in_sizes, int n_in,
                              void* d_out, int out_size, void* d_ws, size_t ws_size,
                              hipStream_t stream) {
  const float* xs    = (const float*)d_in[0];
  const float* A     = (const float*)d_in[1];
  const float* S     = (const float*)d_in[2];
  const float* W     = (const float*)d_in[3];
  const float* gamma = (const float*)d_in[4];
  const float* beta  = (const float*)d_in[5];
  float* out = (float*)d_out;
  char* ws = (char*)d_ws;
  unsigned short* sct  = (unsigned short*)ws;                                // 64 MB sc_t[b][l][j] bf16
  unsigned short* smix = (unsigned short*)(ws + (size_t)64 * 1024 * 1024);   // 64 MB smix[b][i][l] bf16
  unsigned short* Wb   = (unsigned short*)(ws + (size_t)128 * 1024 * 1024);  // 2 MB W bf16
  float* scale = (float*)(ws + (size_t)130 * 1024 * 1024);                   // 4 KB
  float* shift = scale + 1024;                                               // 4 KB

  hipLaunchKernelGGL(k_wconv, dim3(1024), dim3(256), 0, stream, W, Wb);
  hipLaunchKernelGGL(k_analysis, dim3(64, 16, 8), dim3(256), 0, stream, xs, A, sct);
  hipLaunchKernelGGL(k_gemm, dim3(8, 32, 8), dim3(256), 0, stream, Wb, sct, smix);
  hipLaunchKernelGGL(k_stats, dim3(1024), dim3(256), 0, stream, smix, gamma, beta, scale, shift);
  hipLaunchKernelGGL(k_synth_sc, dim3(8192), dim3(256), 0, stream, smix, S, scale, shift, out);
  hipLaunchKernelGGL(k_synth_det, dim3(8192), dim3(256), 0, stream, xs, A, S, out);
}